// Round 1
// baseline (12751.974 us; speedup 1.0000x reference)
//
#include <hip/hip_runtime.h>
#include <math.h>

#define NN 100000
#define NE 1600000
#define IN_DIM 128
#define CO 4
#define HID 64
#define EDIM 16
#define NSTEPS 8
#define NEG_SLOPE 0.2f

// ws layout (float offsets)
#define OFF_H    0          // NN*4
#define OFF_HS   400000     // NN
#define OFF_HD   500000     // NN
#define OFF_DEN  600000     // NN
#define OFF_XG   700000     // NN*4
#define OFF_P    1100000    // NE+NN
#define OFF_W1T  2800000    // 24*64
#define OFF_W2T  2801536    // 64*64

__global__ void prep_kernel(const float* __restrict__ W1, const float* __restrict__ W2,
                            float* __restrict__ W1t, float* __restrict__ W2t) {
    int t = threadIdx.x;
    for (int idx = t; idx < 24 * HID; idx += 256) {
        int d = idx / HID, j = idx % HID;
        W1t[j * 24 + d] = W1[idx];
    }
    for (int idx = t; idx < HID * HID; idx += 256) {
        int i = idx / HID, j = idx % HID;
        W2t[j * HID + i] = W2[idx];
    }
}

__global__ void node_kernel(const float* __restrict__ x, const float* __restrict__ Wg,
                            const float* __restrict__ a_src, const float* __restrict__ a_dst,
                            const float* __restrict__ b_gat,
                            float* __restrict__ h, float* __restrict__ hs,
                            float* __restrict__ hd, float* __restrict__ den,
                            float* __restrict__ xg) {
    int i = blockIdx.x * blockDim.x + threadIdx.x;
    if (i >= NN) return;
    float acc0 = 0.f, acc1 = 0.f, acc2 = 0.f, acc3 = 0.f;
    const float* xr = x + (size_t)i * IN_DIM;
#pragma unroll
    for (int d = 0; d < IN_DIM; d += 4) {
        float4 xv = *(const float4*)(xr + d);
        acc0 = fmaf(xv.x, Wg[(d + 0) * 4 + 0], acc0);
        acc1 = fmaf(xv.x, Wg[(d + 0) * 4 + 1], acc1);
        acc2 = fmaf(xv.x, Wg[(d + 0) * 4 + 2], acc2);
        acc3 = fmaf(xv.x, Wg[(d + 0) * 4 + 3], acc3);
        acc0 = fmaf(xv.y, Wg[(d + 1) * 4 + 0], acc0);
        acc1 = fmaf(xv.y, Wg[(d + 1) * 4 + 1], acc1);
        acc2 = fmaf(xv.y, Wg[(d + 1) * 4 + 2], acc2);
        acc3 = fmaf(xv.y, Wg[(d + 1) * 4 + 3], acc3);
        acc0 = fmaf(xv.z, Wg[(d + 2) * 4 + 0], acc0);
        acc1 = fmaf(xv.z, Wg[(d + 2) * 4 + 1], acc1);
        acc2 = fmaf(xv.z, Wg[(d + 2) * 4 + 2], acc2);
        acc3 = fmaf(xv.z, Wg[(d + 2) * 4 + 3], acc3);
        acc0 = fmaf(xv.w, Wg[(d + 3) * 4 + 0], acc0);
        acc1 = fmaf(xv.w, Wg[(d + 3) * 4 + 1], acc1);
        acc2 = fmaf(xv.w, Wg[(d + 3) * 4 + 2], acc2);
        acc3 = fmaf(xv.w, Wg[(d + 3) * 4 + 3], acc3);
    }
    float4 hv = make_float4(acc0, acc1, acc2, acc3);
    *(float4*)(h + (size_t)i * 4) = hv;
    hs[i] = acc0 * a_src[0] + acc1 * a_src[1] + acc2 * a_src[2] + acc3 * a_src[3];
    hd[i] = acc0 * a_dst[0] + acc1 * a_dst[1] + acc2 * a_dst[2] + acc3 * a_dst[3];
    den[i] = 0.f;
    *(float4*)(xg + (size_t)i * 4) = make_float4(b_gat[0], b_gat[1], b_gat[2], b_gat[3]);
}

// softmax numerator + denominator (softmax is shift-invariant; logits are O(1) here,
// matching reference alpha exactly in exact arithmetic)
__global__ void att_kernel(const int* __restrict__ ei, const float* __restrict__ hs,
                           const float* __restrict__ hd, float* __restrict__ p,
                           float* __restrict__ den) {
    int e = blockIdx.x * blockDim.x + threadIdx.x;
    if (e >= NE + NN) return;
    int r, c;
    if (e < NE) { r = ei[e]; c = ei[NE + e]; }
    else { r = e - NE; c = r; }
    float v = hs[r] + hd[c];
    v = (v >= 0.f) ? v : NEG_SLOPE * v;
    float pe = expf(v);
    p[e] = pe;
    atomicAdd(&den[c], pe);
}

__global__ void agg_kernel(const int* __restrict__ ei, const float* __restrict__ h,
                           const float* __restrict__ p, const float* __restrict__ den,
                           float* __restrict__ xg) {
    int e = blockIdx.x * blockDim.x + threadIdx.x;
    if (e >= NE + NN) return;
    int r, c;
    if (e < NE) { r = ei[e]; c = ei[NE + e]; }
    else { r = e - NE; c = r; }
    float alpha = p[e] / den[c];
    float4 hv = *(const float4*)(h + (size_t)r * 4);
    atomicAdd(&xg[4 * c + 0], hv.x * alpha);
    atomicAdd(&xg[4 * c + 1], hv.y * alpha);
    atomicAdd(&xg[4 * c + 2], hv.z * alpha);
    atomicAdd(&xg[4 * c + 3], hv.w * alpha);
}

__global__ __launch_bounds__(256) void rk4_kernel(
    const int* __restrict__ ei, const float* __restrict__ ea,
    const float* __restrict__ xg,
    const float* __restrict__ W1t, const float* __restrict__ b1,
    const float* __restrict__ W2t, const float* __restrict__ b2,
    const float* __restrict__ W3, const float* __restrict__ b3,
    float* __restrict__ out) {
    int e = blockIdx.x * blockDim.x + threadIdx.x;
    if (e >= NE) return;
    int r = ei[e], c = ei[NE + e];
    float4 s4 = *(const float4*)(xg + (size_t)r * 4);
    float4 t4 = *(const float4*)(xg + (size_t)c * 4);
    float f[8] = {s4.x, s4.y, s4.z, s4.w, t4.x, t4.y, t4.z, t4.w};

    float y[16];
    {
        const float4* yv = (const float4*)(ea + (size_t)e * EDIM);
        float4 y0 = yv[0], y1 = yv[1], y2 = yv[2], y3 = yv[3];
        y[0] = y0.x; y[1] = y0.y; y[2] = y0.z; y[3] = y0.w;
        y[4] = y1.x; y[5] = y1.y; y[6] = y1.z; y[7] = y1.w;
        y[8] = y2.x; y[9] = y2.y; y[10] = y2.z; y[11] = y2.w;
        y[12] = y3.x; y[13] = y3.y; y[14] = y3.z; y[15] = y3.w;
    }

    const float dt = 1.0f / NSTEPS;

#pragma unroll 1
    for (int step = 0; step < NSTEPS; ++step) {
        float arg[16], accum[16];
#pragma unroll
        for (int d = 0; d < 16; ++d) { arg[d] = y[d]; accum[d] = 0.f; }

#pragma unroll 1
        for (int s = 0; s < 4; ++s) {
            // ---- rhs(arg) -> kk ----
            float h1v[HID];
#pragma unroll
            for (int j = 0; j < HID; ++j) {
                float a = b1[j];
#pragma unroll
                for (int d = 0; d < 8; ++d) a = fmaf(f[d], W1t[j * 24 + d], a);
#pragma unroll
                for (int d = 0; d < 16; ++d) a = fmaf(arg[d], W1t[j * 24 + 8 + d], a);
                h1v[j] = fmaxf(a, 0.f);
            }

            float kk[16];
#pragma unroll
            for (int d = 0; d < 16; ++d) kk[d] = b3[d];

#pragma unroll 1
            for (int jb = 0; jb < 16; ++jb) {
                float a0 = b2[jb * 4 + 0];
                float a1 = b2[jb * 4 + 1];
                float a2 = b2[jb * 4 + 2];
                float a3 = b2[jb * 4 + 3];
#pragma unroll
                for (int i = 0; i < HID; ++i) {
                    float hv = h1v[i];
                    a0 = fmaf(hv, W2t[(jb * 4 + 0) * HID + i], a0);
                    a1 = fmaf(hv, W2t[(jb * 4 + 1) * HID + i], a1);
                    a2 = fmaf(hv, W2t[(jb * 4 + 2) * HID + i], a2);
                    a3 = fmaf(hv, W2t[(jb * 4 + 3) * HID + i], a3);
                }
                a0 = fmaxf(a0, 0.f);
                a1 = fmaxf(a1, 0.f);
                a2 = fmaxf(a2, 0.f);
                a3 = fmaxf(a3, 0.f);
#pragma unroll
                for (int d = 0; d < 16; ++d) {
                    kk[d] = fmaf(a0, W3[(jb * 4 + 0) * EDIM + d], kk[d]);
                    kk[d] = fmaf(a1, W3[(jb * 4 + 1) * EDIM + d], kk[d]);
                    kk[d] = fmaf(a2, W3[(jb * 4 + 2) * EDIM + d], kk[d]);
                    kk[d] = fmaf(a3, W3[(jb * 4 + 3) * EDIM + d], kk[d]);
                }
            }
            // ---- RK4 stage combine ----
            float wk = (s == 1 || s == 2) ? 2.0f : 1.0f;
            float cs = (s <= 1) ? (0.5f * dt) : ((s == 2) ? dt : 0.0f);
#pragma unroll
            for (int d = 0; d < 16; ++d) {
                accum[d] = fmaf(wk, kk[d], accum[d]);
                arg[d] = fmaf(cs, kk[d], y[d]);
            }
        }
#pragma unroll
        for (int d = 0; d < 16; ++d) y[d] = fmaf(dt / 6.0f, accum[d], y[d]);
    }

    float4* ov = (float4*)(out + (size_t)e * EDIM);
    ov[0] = make_float4(y[0], y[1], y[2], y[3]);
    ov[1] = make_float4(y[4], y[5], y[6], y[7]);
    ov[2] = make_float4(y[8], y[9], y[10], y[11]);
    ov[3] = make_float4(y[12], y[13], y[14], y[15]);
}

extern "C" void kernel_launch(void* const* d_in, const int* in_sizes, int n_in,
                              void* d_out, int out_size, void* d_ws, size_t ws_size,
                              hipStream_t stream) {
    const float* x     = (const float*)d_in[0];
    const int*   ei    = (const int*)d_in[1];
    const float* ea    = (const float*)d_in[2];
    const float* Wg    = (const float*)d_in[3];
    const float* a_src = (const float*)d_in[4];
    const float* a_dst = (const float*)d_in[5];
    const float* b_gat = (const float*)d_in[6];
    const float* W1    = (const float*)d_in[7];
    const float* b1    = (const float*)d_in[8];
    const float* W2    = (const float*)d_in[9];
    const float* b2    = (const float*)d_in[10];
    const float* W3    = (const float*)d_in[11];
    const float* b3    = (const float*)d_in[12];

    float* ws  = (float*)d_ws;
    float* h   = ws + OFF_H;
    float* hs  = ws + OFF_HS;
    float* hd  = ws + OFF_HD;
    float* den = ws + OFF_DEN;
    float* xg  = ws + OFF_XG;
    float* p   = ws + OFF_P;
    float* W1t = ws + OFF_W1T;
    float* W2t = ws + OFF_W2T;

    prep_kernel<<<1, 256, 0, stream>>>(W1, W2, W1t, W2t);
    node_kernel<<<(NN + 255) / 256, 256, 0, stream>>>(x, Wg, a_src, a_dst, b_gat,
                                                      h, hs, hd, den, xg);
    int ne_tot = NE + NN;
    att_kernel<<<(ne_tot + 255) / 256, 256, 0, stream>>>(ei, hs, hd, p, den);
    agg_kernel<<<(ne_tot + 255) / 256, 256, 0, stream>>>(ei, h, p, den, xg);
    rk4_kernel<<<(NE + 255) / 256, 256, 0, stream>>>(ei, ea, xg, W1t, b1, W2t, b2,
                                                     (const float*)d_in[11], b3,
                                                     (float*)d_out);
}

// Round 2
// 1208.527 us; speedup vs baseline: 10.5517x; 10.5517x over previous
//
#include <hip/hip_runtime.h>
#include <math.h>
#include <stdint.h>

#define NN 100000
#define NE 1600000
#define IN_DIM 128
#define HID 64
#define EDIM 16
#define NEG_SLOPE 0.2f

// ws layout (float offsets)
#define OFF_H    0          // NN*4
#define OFF_HS   400000     // NN
#define OFF_HD   500000     // NN
#define OFF_DEN  600000     // NN
#define OFF_XG   700000     // NN*4
#define OFF_P    1100000    // NE+NN  (ends at 2800000)
#define OFF_IMG  2800000    // 19*256 u32 = 4864

typedef __attribute__((ext_vector_type(8))) short bf16x8;
typedef __attribute__((ext_vector_type(4))) float f32x4;

#define MFMA16(A, B, C) __builtin_amdgcn_mfma_f32_16x16x32_bf16((A), (B), (C), 0, 0, 0)

__device__ inline uint32_t cvtpk(float lo, float hi) {
    uint32_t r;
    asm("v_cvt_pk_bf16_f32 %0, %1, %2" : "=v"(r) : "v"(lo), "v"(hi));
    return r;
}
__device__ inline bf16x8 as_bf(uint4 x) { union { uint4 a; bf16x8 b; } u; u.a = x; return u.b; }

// ---------------- GAT conv (unchanged from r1, passed) ----------------
__global__ void node_kernel(const float* __restrict__ x, const float* __restrict__ Wg,
                            const float* __restrict__ a_src, const float* __restrict__ a_dst,
                            const float* __restrict__ b_gat,
                            float* __restrict__ h, float* __restrict__ hs,
                            float* __restrict__ hd, float* __restrict__ den,
                            float* __restrict__ xg) {
    int i = blockIdx.x * blockDim.x + threadIdx.x;
    if (i >= NN) return;
    float acc0 = 0.f, acc1 = 0.f, acc2 = 0.f, acc3 = 0.f;
    const float* xr = x + (size_t)i * IN_DIM;
#pragma unroll
    for (int d = 0; d < IN_DIM; d += 4) {
        float4 xv = *(const float4*)(xr + d);
        acc0 = fmaf(xv.x, Wg[(d + 0) * 4 + 0], acc0);
        acc1 = fmaf(xv.x, Wg[(d + 0) * 4 + 1], acc1);
        acc2 = fmaf(xv.x, Wg[(d + 0) * 4 + 2], acc2);
        acc3 = fmaf(xv.x, Wg[(d + 0) * 4 + 3], acc3);
        acc0 = fmaf(xv.y, Wg[(d + 1) * 4 + 0], acc0);
        acc1 = fmaf(xv.y, Wg[(d + 1) * 4 + 1], acc1);
        acc2 = fmaf(xv.y, Wg[(d + 1) * 4 + 2], acc2);
        acc3 = fmaf(xv.y, Wg[(d + 1) * 4 + 3], acc3);
        acc0 = fmaf(xv.z, Wg[(d + 2) * 4 + 0], acc0);
        acc1 = fmaf(xv.z, Wg[(d + 2) * 4 + 1], acc1);
        acc2 = fmaf(xv.z, Wg[(d + 2) * 4 + 2], acc2);
        acc3 = fmaf(xv.z, Wg[(d + 2) * 4 + 3], acc3);
        acc0 = fmaf(xv.w, Wg[(d + 3) * 4 + 0], acc0);
        acc1 = fmaf(xv.w, Wg[(d + 3) * 4 + 1], acc1);
        acc2 = fmaf(xv.w, Wg[(d + 3) * 4 + 2], acc2);
        acc3 = fmaf(xv.w, Wg[(d + 3) * 4 + 3], acc3);
    }
    *(float4*)(h + (size_t)i * 4) = make_float4(acc0, acc1, acc2, acc3);
    hs[i] = acc0 * a_src[0] + acc1 * a_src[1] + acc2 * a_src[2] + acc3 * a_src[3];
    hd[i] = acc0 * a_dst[0] + acc1 * a_dst[1] + acc2 * a_dst[2] + acc3 * a_dst[3];
    den[i] = 0.f;
    *(float4*)(xg + (size_t)i * 4) = make_float4(b_gat[0], b_gat[1], b_gat[2], b_gat[3]);
}

__global__ void att_kernel(const int* __restrict__ ei, const float* __restrict__ hs,
                           const float* __restrict__ hd, float* __restrict__ p,
                           float* __restrict__ den) {
    int e = blockIdx.x * blockDim.x + threadIdx.x;
    if (e >= NE + NN) return;
    int r, c;
    if (e < NE) { r = ei[e]; c = ei[NE + e]; }
    else { r = e - NE; c = r; }
    float v = hs[r] + hd[c];
    v = (v >= 0.f) ? v : NEG_SLOPE * v;
    float pe = expf(v);
    p[e] = pe;
    atomicAdd(&den[c], pe);
}

__global__ void agg_kernel(const int* __restrict__ ei, const float* __restrict__ h,
                           const float* __restrict__ p, const float* __restrict__ den,
                           float* __restrict__ xg) {
    int e = blockIdx.x * blockDim.x + threadIdx.x;
    if (e >= NE + NN) return;
    int r, c;
    if (e < NE) { r = ei[e]; c = ei[NE + e]; }
    else { r = e - NE; c = r; }
    float alpha = p[e] / den[c];
    float4 hv = *(const float4*)(h + (size_t)r * 4);
    atomicAdd(&xg[4 * c + 0], hv.x * alpha);
    atomicAdd(&xg[4 * c + 1], hv.y * alpha);
    atomicAdd(&xg[4 * c + 2], hv.z * alpha);
    atomicAdd(&xg[4 * c + 3], hv.w * alpha);
}

// ---------------- fragment image prep ----------------
// Per-lane MFMA A-fragments for W1 (bias-folded into K-pad row 24), W2, W3, plus
// f32 bias C-in vectors b2/b3. Image layout: img[i4*256 + lane*4 + j], i4=0..18:
//   i4 0..3 : W1 frag q          (bf16 pairs, k = 8g+2*j2 .. +1, m = 16q+e)
//   i4 4..11: W2 frag (t*4+q)    (k = 32t+8g+2*j2, m = 16q+e)
//   i4 12,13: W3 frag t          (k = 32t+8g+2*j2, m = e)
//   i4 14..17: b2 frag q (f32: b2[16q+4g+r]) ; i4 18: b3 (b3[4g+r])
__device__ inline uint16_t f2bf_rne(float f) {
    uint32_t x = __float_as_uint(f);
    uint32_t r = x + 0x7FFFu + ((x >> 16) & 1u);
    return (uint16_t)(r >> 16);
}
__device__ inline uint32_t pk2(float lo, float hi) {
    return (uint32_t)f2bf_rne(lo) | ((uint32_t)f2bf_rne(hi) << 16);
}

__global__ void prep_kernel(const float* __restrict__ W1, const float* __restrict__ b1,
                            const float* __restrict__ W2, const float* __restrict__ b2,
                            const float* __restrict__ W3, const float* __restrict__ b3,
                            uint32_t* __restrict__ img) {
    int l = threadIdx.x;
    if (l >= 64) return;
    int e = l & 15, g = l >> 4;
    for (int q = 0; q < 4; ++q) {
        int m = 16 * q + e;
        for (int j2 = 0; j2 < 4; ++j2) {
            int k0 = 8 * g + 2 * j2, k1 = k0 + 1;
            float a = (k0 < 24) ? W1[k0 * 64 + m] : (k0 == 24 ? b1[m] : 0.f);
            float b = (k1 < 24) ? W1[k1 * 64 + m] : (k1 == 24 ? b1[m] : 0.f);
            img[q * 256 + l * 4 + j2] = pk2(a, b);
        }
    }
    for (int t = 0; t < 2; ++t)
        for (int q = 0; q < 4; ++q) {
            int m = 16 * q + e;
            for (int j2 = 0; j2 < 4; ++j2) {
                int k0 = 32 * t + 8 * g + 2 * j2;
                img[(4 + t * 4 + q) * 256 + l * 4 + j2] =
                    pk2(W2[k0 * 64 + m], W2[(k0 + 1) * 64 + m]);
            }
        }
    for (int t = 0; t < 2; ++t)
        for (int j2 = 0; j2 < 4; ++j2) {
            int k0 = 32 * t + 8 * g + 2 * j2;
            img[(12 + t) * 256 + l * 4 + j2] =
                pk2(W3[k0 * 16 + e], W3[(k0 + 1) * 16 + e]);
        }
    for (int q = 0; q < 4; ++q)
        for (int r = 0; r < 4; ++r)
            img[(14 + q) * 256 + l * 4 + r] = __float_as_uint(b2[16 * q + 4 * g + r]);
    for (int r = 0; r < 4; ++r)
        img[18 * 256 + l * 4 + r] = __float_as_uint(b3[4 * g + r]);
}

// ---------------- RK4 over the edge MLP, MFMA version ----------------
// Wave = 16 edges. All layers computed transposed: D[feat][edge] = W^T x X.
// mfma_f32_16x16x32_bf16: A row = lane&15, k = 8*(lane>>4)+j (contiguous);
// C/D: col = lane&15 (edge), row = 4*(lane>>4)+reg (feature).
// LDS u32 regions per wave (stride *4-aligned for b128, padded for banks):
//   f    [0,128)   : [e][4 pairs] stride 8  (src4|tgt4, bf16 pairs, written once)
//   ones [128,256) : [e][4 pairs] stride 8  (pair0 = 1.0 -> bias row k=24)
//   arg  [256,448) : [e][8 pairs] stride 12
//   h1   [448,1024): [e][32 pairs] stride 36
//   h2   [1024,1600): same
__global__ __launch_bounds__(256, 3) void rk4_kernel(
    const int* __restrict__ ei, const float* __restrict__ ea,
    const float* __restrict__ xg, const uint32_t* __restrict__ img,
    float* __restrict__ out) {
    __shared__ uint32_t sm[4][1600];
    const int tid = threadIdx.x;
    const int w = tid >> 6, l = tid & 63;
    const int e = l & 15, g = l >> 4;
    uint32_t* S = sm[w];
    const int edge = blockIdx.x * 64 + w * 16 + e;

    // weight fragments (persistent registers)
    bf16x8 W1f[4], W2f[2][4], W3f[2];
    f32x4 b2f[4], b3f;
    {
        union { uint4 a; bf16x8 b; f32x4 f; } t;
#pragma unroll
        for (int q = 0; q < 4; ++q) { t.a = *(const uint4*)(img + q * 256 + l * 4); W1f[q] = t.b; }
#pragma unroll
        for (int tt = 0; tt < 2; ++tt)
#pragma unroll
            for (int q = 0; q < 4; ++q) {
                t.a = *(const uint4*)(img + (4 + tt * 4 + q) * 256 + l * 4);
                W2f[tt][q] = t.b;
            }
#pragma unroll
        for (int tt = 0; tt < 2; ++tt) { t.a = *(const uint4*)(img + (12 + tt) * 256 + l * 4); W3f[tt] = t.b; }
#pragma unroll
        for (int q = 0; q < 4; ++q) { t.a = *(const uint4*)(img + (14 + q) * 256 + l * 4); b2f[q] = t.f; }
        t.a = *(const uint4*)(img + 18 * 256 + l * 4); b3f = t.f;
    }

    // LDS init: ones region + f (gathered GAT outputs), same-wave only
    S[128 + 8 * e + g] = (g == 0) ? 0x00003F80u : 0u;  // bf16(1.0) in low half of pair0
    if (g < 2) {
        int idx = ei[(g ? NE : 0) + edge];
        float4 xv = *(const float4*)(xg + (size_t)idx * 4);
        uint2 pk; pk.x = cvtpk(xv.x, xv.y); pk.y = cvtpk(xv.z, xv.w);
        *(uint2*)&S[8 * e + 2 * g] = pk;
    }

    float4 y4 = *(const float4*)(ea + (size_t)edge * 16 + 4 * g);
    float y0 = y4.x, y1 = y4.y, y2 = y4.z, y3 = y4.w;

    const int b1idx = (g == 0) ? 8 * e : (g == 3) ? 128 + 8 * e : 256 + 12 * e + 4 * (g - 1);
    const int argW = 256 + 12 * e + 2 * g;
    const int h1B = 448 + 36 * e;
    const int h2B = 1024 + 36 * e;
    const f32x4 zero4 = {0.f, 0.f, 0.f, 0.f};
    const float dt6 = 0.125f / 6.0f;

#define RELUPK(HV, BASE, Q)                                                      \
    {                                                                            \
        float m0 = fmaxf((HV)[0], 0.f), m1 = fmaxf((HV)[1], 0.f);                \
        float m2 = fmaxf((HV)[2], 0.f), m3 = fmaxf((HV)[3], 0.f);                \
        uint2 hp; hp.x = cvtpk(m0, m1); hp.y = cvtpk(m2, m3);                    \
        *(uint2*)&S[(BASE) + 8 * (Q) + 2 * g] = hp;                              \
    }

#pragma unroll 1
    for (int step = 0; step < 8; ++step) {
        float a0 = y0, a1 = y1, a2 = y2, a3 = y3;
        float c0 = 0.f, c1 = 0.f, c2 = 0.f, c3 = 0.f;
#pragma unroll 1
        for (int s = 0; s < 4; ++s) {
            // stage input -> LDS (bf16 pairs)
            { uint2 ap; ap.x = cvtpk(a0, a1); ap.y = cvtpk(a2, a3);
              *(uint2*)&S[argW] = ap; }
            // layer 1 (K=32, bias folded via ones row)
            bf16x8 B1 = as_bf(*(const uint4*)&S[b1idx]);
            f32x4 h0 = MFMA16(W1f[0], B1, zero4);
            f32x4 h1 = MFMA16(W1f[1], B1, zero4);
            f32x4 h2 = MFMA16(W1f[2], B1, zero4);
            f32x4 h3 = MFMA16(W1f[3], B1, zero4);
            RELUPK(h0, h1B, 0) RELUPK(h1, h1B, 1) RELUPK(h2, h1B, 2) RELUPK(h3, h1B, 3)
            // layer 2 (K=64, bias via C-in)
            bf16x8 B20 = as_bf(*(const uint4*)&S[h1B + 4 * g]);
            bf16x8 B21 = as_bf(*(const uint4*)&S[h1B + 16 + 4 * g]);
            f32x4 p0 = MFMA16(W2f[0][0], B20, b2f[0]); p0 = MFMA16(W2f[1][0], B21, p0);
            f32x4 p1 = MFMA16(W2f[0][1], B20, b2f[1]); p1 = MFMA16(W2f[1][1], B21, p1);
            f32x4 p2 = MFMA16(W2f[0][2], B20, b2f[2]); p2 = MFMA16(W2f[1][2], B21, p2);
            f32x4 p3 = MFMA16(W2f[0][3], B20, b2f[3]); p3 = MFMA16(W2f[1][3], B21, p3);
            RELUPK(p0, h2B, 0) RELUPK(p1, h2B, 1) RELUPK(p2, h2B, 2) RELUPK(p3, h2B, 3)
            // layer 3 (K=64, N=16)
            bf16x8 B30 = as_bf(*(const uint4*)&S[h2B + 4 * g]);
            bf16x8 B31 = as_bf(*(const uint4*)&S[h2B + 16 + 4 * g]);
            f32x4 kk = MFMA16(W3f[0], B30, b3f);
            kk = MFMA16(W3f[1], B31, kk);
            // RK4 stage combine (lane owns feats 4g..4g+3 of its edge)
            float wk = (s == 1 || s == 2) ? 2.f : 1.f;
            float cs = (s < 2) ? 0.0625f : (s == 2) ? 0.125f : 0.f;
            c0 = fmaf(wk, kk[0], c0); c1 = fmaf(wk, kk[1], c1);
            c2 = fmaf(wk, kk[2], c2); c3 = fmaf(wk, kk[3], c3);
            a0 = fmaf(cs, kk[0], y0); a1 = fmaf(cs, kk[1], y1);
            a2 = fmaf(cs, kk[2], y2); a3 = fmaf(cs, kk[3], y3);
        }
        y0 = fmaf(dt6, c0, y0); y1 = fmaf(dt6, c1, y1);
        y2 = fmaf(dt6, c2, y2); y3 = fmaf(dt6, c3, y3);
    }
#undef RELUPK
    *(float4*)(out + (size_t)edge * 16 + 4 * g) = make_float4(y0, y1, y2, y3);
}

extern "C" void kernel_launch(void* const* d_in, const int* in_sizes, int n_in,
                              void* d_out, int out_size, void* d_ws, size_t ws_size,
                              hipStream_t stream) {
    const float* x     = (const float*)d_in[0];
    const int*   ei    = (const int*)d_in[1];
    const float* ea    = (const float*)d_in[2];
    const float* Wg    = (const float*)d_in[3];
    const float* a_src = (const float*)d_in[4];
    const float* a_dst = (const float*)d_in[5];
    const float* b_gat = (const float*)d_in[6];
    const float* W1    = (const float*)d_in[7];
    const float* b1    = (const float*)d_in[8];
    const float* W2    = (const float*)d_in[9];
    const float* b2    = (const float*)d_in[10];
    const float* W3    = (const float*)d_in[11];
    const float* b3    = (const float*)d_in[12];

    float* ws  = (float*)d_ws;
    float* h   = ws + OFF_H;
    float* hs  = ws + OFF_HS;
    float* hd  = ws + OFF_HD;
    float* den = ws + OFF_DEN;
    float* xg  = ws + OFF_XG;
    float* p   = ws + OFF_P;
    uint32_t* img = (uint32_t*)(ws + OFF_IMG);

    prep_kernel<<<1, 64, 0, stream>>>(W1, b1, W2, b2, W3, b3, img);
    node_kernel<<<(NN + 255) / 256, 256, 0, stream>>>(x, Wg, a_src, a_dst, b_gat,
                                                      h, hs, hd, den, xg);
    int ne_tot = NE + NN;
    att_kernel<<<(ne_tot + 255) / 256, 256, 0, stream>>>(ei, hs, hd, p, den);
    agg_kernel<<<(ne_tot + 255) / 256, 256, 0, stream>>>(ei, h, p, den, xg);
    rk4_kernel<<<NE / 64, 256, 0, stream>>>(ei, ea, xg, img, (float*)d_out);
}